// Round 1
// baseline (2087.365 us; speedup 1.0000x reference)
//
#include <hip/hip_runtime.h>
#include <hip/hip_bf16.h>
#include <cstdint>
#include <cstddef>

typedef __bf16 bf16;
typedef __attribute__((ext_vector_type(8))) __bf16 bf16x8;
typedef __attribute__((ext_vector_type(4))) __bf16 bf16x4;
typedef __attribute__((ext_vector_type(4))) float f32x4;

__device__ __forceinline__ f32x4 mfma16(bf16x8 a, bf16x8 b, f32x4 c) {
    return __builtin_amdgcn_mfma_f32_16x16x32_bf16(a, b, c, 0, 0, 0);
}

__device__ __forceinline__ void async_copy16(const void* g, void* l) {
    __builtin_amdgcn_global_load_lds((const __attribute__((address_space(1))) void*)g,
                                     (__attribute__((address_space(3))) void*)l,
                                     16, 0, 0);
}

// ---------------- embedding: x[row][h] = tok_emb[id][h] + pos_emb[s][h] ----------------
__global__ __launch_bounds__(256)
void embed_kernel(const int* __restrict__ ids, const float* __restrict__ te,
                  const float* __restrict__ pe, float* __restrict__ x)
{
    const int row = blockIdx.x;          // 0..2047 = b*1024+s
    const int s = row & 1023;
    const int id = ids[row];
    const f32x4* a = (const f32x4*)(te + (size_t)id * 1024);
    const f32x4* b = (const f32x4*)(pe + (size_t)s * 1024);
    f32x4* o = (f32x4*)(x + (size_t)row * 1024);
    o[threadIdx.x] = a[threadIdx.x] + b[threadIdx.x];
}

// ---------------- layernorm: out(bf16) = (x-m)*rstd*s + b ----------------
__global__ __launch_bounds__(256)
void ln_kernel(const float* __restrict__ x, const float* __restrict__ sc,
               const float* __restrict__ bi, bf16* __restrict__ out)
{
    const int row = blockIdx.x, t = threadIdx.x;
    const f32x4 v = ((const f32x4*)(x + (size_t)row * 1024))[t];
    float s = v[0] + v[1] + v[2] + v[3];
    float q = v[0]*v[0] + v[1]*v[1] + v[2]*v[2] + v[3]*v[3];
    #pragma unroll
    for (int o = 1; o < 64; o <<= 1) { s += __shfl_xor(s, o); q += __shfl_xor(q, o); }
    __shared__ float red[8];
    const int wv = t >> 6, lane = t & 63;
    if (lane == 0) { red[wv] = s; red[4 + wv] = q; }
    __syncthreads();
    s = red[0] + red[1] + red[2] + red[3];
    q = red[4] + red[5] + red[6] + red[7];
    const float mean = s * (1.f / 1024.f);
    const float var  = q * (1.f / 1024.f) - mean * mean;
    const float rstd = rsqrtf(var + 1e-5f);
    const f32x4 scv = ((const f32x4*)sc)[t];
    const f32x4 biv = ((const f32x4*)bi)[t];
    bf16x4 o4;
    #pragma unroll
    for (int j = 0; j < 4; j++) o4[j] = (bf16)((v[j] - mean) * rstd * scv[j] + biv[j]);
    *(bf16x4*)(out + (size_t)row * 1024 + t * 4) = o4;
}

// ---------------- weight transpose+convert: BT[n][k] (bf16) = W[k][n] (f32) ----------------
__global__ __launch_bounds__(256)
void wcvt_kernel(const float* __restrict__ W, bf16* __restrict__ BT, int K, int N)
{
    __shared__ float tile[32][33];
    const int n0 = blockIdx.x << 5, k0 = blockIdx.y << 5;
    const int tx = threadIdx.x & 31, ty = threadIdx.x >> 5;   // ty 0..7
    #pragma unroll
    for (int r = 0; r < 4; r++)
        tile[ty + r*8][tx] = W[(size_t)(k0 + ty + r*8) * N + n0 + tx];
    __syncthreads();
    #pragma unroll
    for (int r = 0; r < 4; r++)
        BT[(size_t)(n0 + ty + r*8) * K + k0 + tx] = (bf16)tile[tx][ty + r*8];
}

// ---------------- GEMM: C[M][N] = A[M][K] (bf16) * BT[N][K]^T (bf16) ----------------
// EPI: 0 = bias -> bf16 out ; 1 = bias + residual add into f32 ; 2 = bias + gelu -> bf16 ; 3 = plain f32
template<int EPI>
__global__ __launch_bounds__(256)
void gemm_kernel(const bf16* __restrict__ A, const bf16* __restrict__ BT,
                 const float* __restrict__ bias, float* __restrict__ resid,
                 bf16* __restrict__ outb, float* __restrict__ outf,
                 int N, int K)
{
    __shared__ __align__(16) bf16 Asmem[128 * 64];
    __shared__ __align__(16) bf16 Bsmem[128 * 64];
    const int bm = blockIdx.x, bn = blockIdx.y;
    const int tid = threadIdx.x;
    const int lane = tid & 63, wave = tid >> 6;
    const int wr = wave >> 1, wc = wave & 1;
    f32x4 acc[4][4];
    #pragma unroll
    for (int m = 0; m < 4; m++)
        #pragma unroll
        for (int n = 0; n < 4; n++) acc[m][n] = f32x4{0.f, 0.f, 0.f, 0.f};

    const bf16* Abase = A  + (size_t)bm * 128 * K;
    const bf16* Bbase = BT + (size_t)bn * 128 * K;
    const int K64 = K >> 6;
    for (int kt = 0; kt < K64; kt++) {
        __syncthreads();
        #pragma unroll
        for (int p = 0; p < 4; p++) {
            const int idx = p * 256 + tid;             // 0..1023 16B chunks
            const int r = idx >> 3, c = (idx & 7) << 3;
            async_copy16(Abase + (size_t)r * K + kt * 64 + c, Asmem + idx * 8);
            async_copy16(Bbase + (size_t)r * K + kt * 64 + c, Bsmem + idx * 8);
        }
        __syncthreads();
        #pragma unroll
        for (int ks = 0; ks < 2; ks++) {
            bf16x8 af[4], bfv[4];
            const int ko = ks * 32 + ((lane >> 4) << 3);
            const int ar = wr * 64 + (lane & 15);
            const int br = wc * 64 + (lane & 15);
            #pragma unroll
            for (int m = 0; m < 4; m++) af[m]  = *(const bf16x8*)&Asmem[(ar + m*16) * 64 + ko];
            #pragma unroll
            for (int n = 0; n < 4; n++) bfv[n] = *(const bf16x8*)&Bsmem[(br + n*16) * 64 + ko];
            #pragma unroll
            for (int m = 0; m < 4; m++)
                #pragma unroll
                for (int n = 0; n < 4; n++)
                    acc[m][n] = mfma16(af[m], bfv[n], acc[m][n]);
        }
    }
    // epilogue: D row = (lane>>4)*4+i, col = lane&15
    const int r0 = bm * 128 + wr * 64 + ((lane >> 4) << 2);
    const int c0 = bn * 128 + wc * 64 + (lane & 15);
    #pragma unroll
    for (int n = 0; n < 4; n++) {
        const int col = c0 + n * 16;
        const float bv = (EPI == 3) ? 0.f : bias[col];
        #pragma unroll
        for (int m = 0; m < 4; m++) {
            const int row = r0 + m * 16;
            const f32x4 a = acc[m][n];
            #pragma unroll
            for (int i = 0; i < 4; i++) {
                const float v = a[i] + bv;
                const size_t off = (size_t)(row + i) * N + col;
                if constexpr (EPI == 0) outb[off] = (bf16)v;
                else if constexpr (EPI == 1) resid[off] += v;
                else if constexpr (EPI == 2) {
                    const float g = 0.5f * v * (1.f + erff(v * 0.70710678118f));
                    outb[off] = (bf16)g;
                } else outf[off] = v;
            }
        }
    }
}

// ---------------- fused non-causal attention (flash-style) ----------------
// grid: (B*NH = 32, S/64 = 16), 256 thr = 4 waves, wave handles 16 q-rows.
__global__ __launch_bounds__(256)
void attn_kernel(const bf16* __restrict__ qkv, bf16* __restrict__ attno)
{
    __shared__ __align__(16) bf16 Vt[64][136];     // V^T chunk: [d][key 0..127], padded
    __shared__ __align__(16) bf16 Plds[4][16][40]; // per-wave P transpose bounce
    const int b = blockIdx.x >> 4, h = blockIdx.x & 15;
    const int qb = blockIdx.y;
    const int tid = threadIdx.x, lane = tid & 63, wave = tid >> 6;
    const bf16* base = qkv + (size_t)b * 1024 * 3072;
    const int qrow0 = qb * 64 + wave * 16;

    bf16x8 aQ[2];
    {
        const int qr = qrow0 + (lane & 15);
        const bf16* qp = base + (size_t)qr * 3072 + h * 64 + ((lane >> 4) << 3);
        aQ[0] = *(const bf16x8*)qp;
        aQ[1] = *(const bf16x8*)(qp + 32);
    }
    float m_i[4] = {-1e30f, -1e30f, -1e30f, -1e30f};
    float l_i[4] = {0.f, 0.f, 0.f, 0.f};
    f32x4 acc[4];
    #pragma unroll
    for (int nb = 0; nb < 4; nb++) acc[nb] = f32x4{0.f, 0.f, 0.f, 0.f};

    for (int ck = 0; ck < 8; ck++) {
        __syncthreads();
        // stage Vt[d][key] for keys ck*128..+128
        #pragma unroll
        for (int p = 0; p < 4; p++) {
            const int idx = p * 256 + tid;
            const int keyl = idx >> 3, dc = idx & 7;
            const bf16x8 v = *(const bf16x8*)&base[(size_t)(ck*128 + keyl) * 3072 + 2048 + h*64 + dc*8];
            #pragma unroll
            for (int e = 0; e < 8; e++) Vt[dc*8 + e][keyl] = v[e];
        }
        __syncthreads();
        for (int kk = 0; kk < 4; kk++) {
            const int key0 = ck * 128 + kk * 32;
            f32x4 s0, s1;
            {
                const int keyA = key0 + (lane & 15);
                const bf16* kp = base + (size_t)keyA * 3072 + 1024 + h * 64 + ((lane >> 4) << 3);
                f32x4 z{0.f, 0.f, 0.f, 0.f};
                z = mfma16(aQ[0], *(const bf16x8*)kp, z);
                z = mfma16(aQ[1], *(const bf16x8*)(kp + 32), z);
                s0 = z;
                const bf16* kp2 = kp + (size_t)16 * 3072;
                f32x4 z2{0.f, 0.f, 0.f, 0.f};
                z2 = mfma16(aQ[0], *(const bf16x8*)kp2, z2);
                z2 = mfma16(aQ[1], *(const bf16x8*)(kp2 + 32), z2);
                s1 = z2;
            }
            float c[4];
            #pragma unroll
            for (int i = 0; i < 4; i++) {
                const float sa = s0[i] * 0.125f, sb = s1[i] * 0.125f;
                float t = fmaxf(sa, sb);
                #pragma unroll
                for (int o = 1; o < 16; o <<= 1) t = fmaxf(t, __shfl_xor(t, o));
                const float mnew = fmaxf(m_i[i], t);
                c[i] = __expf(m_i[i] - mnew);
                const float p0 = __expf(sa - mnew), p1 = __expf(sb - mnew);
                float rs = p0 + p1;
                #pragma unroll
                for (int o = 1; o < 16; o <<= 1) rs += __shfl_xor(rs, o);
                l_i[i] = l_i[i] * c[i] + rs;
                m_i[i] = mnew;
                const int pr = ((lane >> 4) << 2) + i;
                Plds[wave][pr][lane & 15]      = (bf16)p0;
                Plds[wave][pr][16 + (lane & 15)] = (bf16)p1;
            }
            #pragma unroll
            for (int nb = 0; nb < 4; nb++) {
                f32x4 a = acc[nb];
                a[0] *= c[0]; a[1] *= c[1]; a[2] *= c[2]; a[3] *= c[3];
                acc[nb] = a;
            }
            const bf16x8 aP = *(const bf16x8*)&Plds[wave][lane & 15][(lane >> 4) << 3];
            #pragma unroll
            for (int nb = 0; nb < 4; nb++) {
                const bf16x8 bV = *(const bf16x8*)&Vt[nb*16 + (lane & 15)][kk*32 + ((lane >> 4) << 3)];
                acc[nb] = mfma16(aP, bV, acc[nb]);
            }
        }
    }
    #pragma unroll
    for (int nb = 0; nb < 4; nb++) {
        #pragma unroll
        for (int i = 0; i < 4; i++) {
            const int row = qrow0 + ((lane >> 4) << 2) + i;
            const float o = acc[nb][i] / l_i[i];
            attno[(size_t)(b*1024 + row) * 1024 + h*64 + nb*16 + (lane & 15)] = (bf16)o;
        }
    }
}

// ---------------- orchestration ----------------
extern "C" void kernel_launch(void* const* d_in, const int* in_sizes, int n_in,
                              void* d_out, int out_size, void* d_ws, size_t ws_size,
                              hipStream_t stream)
{
    const int*   ids     = (const int*)  d_in[0];
    const float* tok_emb = (const float*)d_in[1];
    const float* pos_emb = (const float*)d_in[2];
    const float* ln1_s   = (const float*)d_in[3];
    const float* ln1_b   = (const float*)d_in[4];
    const float* qkv_w   = (const float*)d_in[5];
    const float* qkv_b   = (const float*)d_in[6];
    const float* out_w   = (const float*)d_in[7];
    const float* out_b   = (const float*)d_in[8];
    const float* ln2_s   = (const float*)d_in[9];
    const float* ln2_b   = (const float*)d_in[10];
    const float* w1      = (const float*)d_in[11];
    const float* b1      = (const float*)d_in[12];
    const float* w2      = (const float*)d_in[13];
    const float* b2      = (const float*)d_in[14];
    const float* lnf_s   = (const float*)d_in[15];
    const float* lnf_b   = (const float*)d_in[16];
    const float* lm_w    = (const float*)d_in[17];

    char* ws = (char*)d_ws;
    float* x    = (float*)ws;  ws += (size_t)2048 * 1024 * 4;
    bf16*  h    = (bf16*)ws;   ws += (size_t)2048 * 1024 * 2;
    bf16*  qkvb = (bf16*)ws;   ws += (size_t)2048 * 3072 * 2;
    bf16*  attno= (bf16*)ws;   ws += (size_t)2048 * 1024 * 2;
    bf16*  ff   = (bf16*)ws;   ws += (size_t)2048 * 4096 * 2;
    bf16*  wT   = (bf16*)ws;   ws += (size_t)32000 * 1024 * 2;

    embed_kernel<<<2048, 256, 0, stream>>>(ids, tok_emb, pos_emb, x);

    for (int l = 0; l < 6; l++) {
        ln_kernel<<<2048, 256, 0, stream>>>(x, ln1_s + l*1024, ln1_b + l*1024, h);
        wcvt_kernel<<<dim3(96, 32), 256, 0, stream>>>(qkv_w + (size_t)l*1024*3072, wT, 1024, 3072);
        gemm_kernel<0><<<dim3(16, 24), 256, 0, stream>>>(h, wT, qkv_b + l*3072, nullptr, qkvb, nullptr, 3072, 1024);
        attn_kernel<<<dim3(32, 16), 256, 0, stream>>>(qkvb, attno);
        wcvt_kernel<<<dim3(32, 32), 256, 0, stream>>>(out_w + (size_t)l*1024*1024, wT, 1024, 1024);
        gemm_kernel<1><<<dim3(16, 8), 256, 0, stream>>>(attno, wT, out_b + l*1024, x, nullptr, nullptr, 1024, 1024);
        ln_kernel<<<2048, 256, 0, stream>>>(x, ln2_s + l*1024, ln2_b + l*1024, h);
        wcvt_kernel<<<dim3(128, 32), 256, 0, stream>>>(w1 + (size_t)l*1024*4096, wT, 1024, 4096);
        gemm_kernel<2><<<dim3(16, 32), 256, 0, stream>>>(h, wT, b1 + l*4096, nullptr, ff, nullptr, 4096, 1024);
        wcvt_kernel<<<dim3(32, 128), 256, 0, stream>>>(w2 + (size_t)l*4096*1024, wT, 4096, 1024);
        gemm_kernel<1><<<dim3(16, 8), 256, 0, stream>>>(ff, wT, b2 + l*1024, x, nullptr, nullptr, 1024, 4096);
    }
    ln_kernel<<<2048, 256, 0, stream>>>(x, lnf_s, lnf_b, h);
    wcvt_kernel<<<dim3(1000, 32), 256, 0, stream>>>(lm_w, wT, 1024, 32000);
    gemm_kernel<3><<<dim3(16, 250), 256, 0, stream>>>(h, wT, nullptr, nullptr, nullptr, (float*)d_out, 32000, 1024);
}

// Round 2
// 1900.183 us; speedup vs baseline: 1.0985x; 1.0985x over previous
//
#include <hip/hip_runtime.h>
#include <hip/hip_bf16.h>
#include <cstdint>
#include <cstddef>

typedef __bf16 bf16;
typedef __attribute__((ext_vector_type(8))) __bf16 bf16x8;
typedef __attribute__((ext_vector_type(4))) __bf16 bf16x4;
typedef __attribute__((ext_vector_type(4))) float f32x4;

__device__ __forceinline__ f32x4 mfma16(bf16x8 a, bf16x8 b, f32x4 c) {
    return __builtin_amdgcn_mfma_f32_16x16x32_bf16(a, b, c, 0, 0, 0);
}

__device__ __forceinline__ void async_copy16(const void* g, void* l) {
    __builtin_amdgcn_global_load_lds((const __attribute__((address_space(1))) void*)g,
                                     (__attribute__((address_space(3))) void*)l,
                                     16, 0, 0);
}

// ---------------- embedding: x[row][h] = tok_emb[id][h] + pos_emb[s][h] ----------------
__global__ __launch_bounds__(256)
void embed_kernel(const int* __restrict__ ids, const float* __restrict__ te,
                  const float* __restrict__ pe, float* __restrict__ x)
{
    const int row = blockIdx.x;          // 0..2047 = b*1024+s
    const int s = row & 1023;
    const int id = ids[row];
    const f32x4* a = (const f32x4*)(te + (size_t)id * 1024);
    const f32x4* b = (const f32x4*)(pe + (size_t)s * 1024);
    f32x4* o = (f32x4*)(x + (size_t)row * 1024);
    o[threadIdx.x] = a[threadIdx.x] + b[threadIdx.x];
}

// ---------------- layernorm: out(bf16) = (x-m)*rstd*s + b ----------------
__global__ __launch_bounds__(256)
void ln_kernel(const float* __restrict__ x, const float* __restrict__ sc,
               const float* __restrict__ bi, bf16* __restrict__ out)
{
    const int row = blockIdx.x, t = threadIdx.x;
    const f32x4 v = ((const f32x4*)(x + (size_t)row * 1024))[t];
    float s = v[0] + v[1] + v[2] + v[3];
    float q = v[0]*v[0] + v[1]*v[1] + v[2]*v[2] + v[3]*v[3];
    #pragma unroll
    for (int o = 1; o < 64; o <<= 1) { s += __shfl_xor(s, o); q += __shfl_xor(q, o); }
    __shared__ float red[8];
    const int wv = t >> 6, lane = t & 63;
    if (lane == 0) { red[wv] = s; red[4 + wv] = q; }
    __syncthreads();
    s = red[0] + red[1] + red[2] + red[3];
    q = red[4] + red[5] + red[6] + red[7];
    const float mean = s * (1.f / 1024.f);
    const float var  = q * (1.f / 1024.f) - mean * mean;
    const float rstd = rsqrtf(var + 1e-5f);
    const f32x4 scv = ((const f32x4*)sc)[t];
    const f32x4 biv = ((const f32x4*)bi)[t];
    bf16x4 o4;
    #pragma unroll
    for (int j = 0; j < 4; j++) o4[j] = (bf16)((v[j] - mean) * rstd * scv[j] + biv[j]);
    *(bf16x4*)(out + (size_t)row * 1024 + t * 4) = o4;
}

// ---------------- weight transpose+convert: BT[n][k] (bf16) = W[k][n] (f32) ----------------
// 64x64 tile, float4 loads, bf16x4 stores. grid: (N/64, K/64)
__global__ __launch_bounds__(256)
void wcvt_kernel(const float* __restrict__ W, bf16* __restrict__ BT, int K, int N)
{
    __shared__ float tile[64][65];
    const int n0 = blockIdx.x << 6, k0 = blockIdx.y << 6;
    const int tx = threadIdx.x & 15, ty = threadIdx.x >> 4;   // ty 0..15
    #pragma unroll
    for (int r = 0; r < 4; r++) {
        const f32x4 v = *(const f32x4*)&W[(size_t)(k0 + ty + r*16) * N + n0 + tx*4];
        tile[ty + r*16][tx*4 + 0] = v[0];
        tile[ty + r*16][tx*4 + 1] = v[1];
        tile[ty + r*16][tx*4 + 2] = v[2];
        tile[ty + r*16][tx*4 + 3] = v[3];
    }
    __syncthreads();
    #pragma unroll
    for (int r = 0; r < 4; r++) {
        const int n = ty + r*16;
        bf16x4 o;
        #pragma unroll
        for (int j = 0; j < 4; j++) o[j] = (bf16)tile[tx*4 + j][n];
        *(bf16x4*)&BT[(size_t)(n0 + n) * K + k0 + tx*4] = o;
    }
}

// ---------------- GEMM: C[M][N] = A[M][K] (bf16) * BT[N][K]^T (bf16), M = 2048 ----------------
// EPI: 0 = bias -> bf16 out ; 1 = bias + residual add into f32 ; 2 = bias + gelu -> bf16 ; 3 = plain f32
// 1D grid = (2048/BM) * (N/BN), bm fastest, XCD-chunked bijective swizzle (m204).
template<int BM, int BN, int EPI>
__global__ __launch_bounds__(256)
void gemm_kernel(const bf16* __restrict__ A, const bf16* __restrict__ BT,
                 const float* __restrict__ bias, float* __restrict__ resid,
                 bf16* __restrict__ outb, float* __restrict__ outf,
                 int N, int K)
{
    constexpr int MT = 2048 / BM;        // m-tiles (pow2)
    constexpr int WM = BM / 2, WN = BN / 2;
    constexpr int FM = WM / 16, FN = WN / 16;
    constexpr int CA = BM / 32, CB = BN / 32;   // 16B chunks per thread per K-tile
    __shared__ __align__(16) bf16 Asmem[BM * 64];
    __shared__ __align__(16) bf16 Bsmem[BN * 64];

    // bijective XCD-chunked swizzle
    const int nwg = gridDim.x;
    const int q = nwg >> 3, rr = nwg & 7;
    const int xcd = blockIdx.x & 7, ix = blockIdx.x >> 3;
    const int nid = (xcd < rr ? xcd * (q + 1) : rr * (q + 1) + (xcd - rr) * q) + ix;
    const int bm = nid % MT, bn = nid / MT;

    const int tid = threadIdx.x;
    const int lane = tid & 63, wave = tid >> 6;
    const int wr = wave >> 1, wc = wave & 1;
    f32x4 acc[FM][FN];
    #pragma unroll
    for (int m = 0; m < FM; m++)
        #pragma unroll
        for (int n = 0; n < FN; n++) acc[m][n] = f32x4{0.f, 0.f, 0.f, 0.f};

    const bf16* Abase = A  + (size_t)bm * BM * K;
    const bf16* Bbase = BT + (size_t)bn * BN * K;
    const int K64 = K >> 6;
    for (int kt = 0; kt < K64; kt++) {
        __syncthreads();
        #pragma unroll
        for (int p = 0; p < CA; p++) {
            const int idx = p * 256 + tid;
            const int r = idx >> 3, c = (idx & 7) << 3;
            async_copy16(Abase + (size_t)r * K + kt * 64 + c, Asmem + idx * 8);
        }
        #pragma unroll
        for (int p = 0; p < CB; p++) {
            const int idx = p * 256 + tid;
            const int r = idx >> 3, c = (idx & 7) << 3;
            async_copy16(Bbase + (size_t)r * K + kt * 64 + c, Bsmem + idx * 8);
        }
        __syncthreads();
        #pragma unroll
        for (int ks = 0; ks < 2; ks++) {
            bf16x8 af[FM], bfv[FN];
            const int ko = ks * 32 + ((lane >> 4) << 3);
            const int ar = wr * WM + (lane & 15);
            const int br = wc * WN + (lane & 15);
            #pragma unroll
            for (int m = 0; m < FM; m++) af[m]  = *(const bf16x8*)&Asmem[(ar + m*16) * 64 + ko];
            #pragma unroll
            for (int n = 0; n < FN; n++) bfv[n] = *(const bf16x8*)&Bsmem[(br + n*16) * 64 + ko];
            #pragma unroll
            for (int m = 0; m < FM; m++)
                #pragma unroll
                for (int n = 0; n < FN; n++)
                    acc[m][n] = mfma16(af[m], bfv[n], acc[m][n]);
        }
    }
    // epilogue: D row = (lane>>4)*4+i, col = lane&15
    const int r0 = bm * BM + wr * WM + ((lane >> 4) << 2);
    const int c0 = bn * BN + wc * WN + (lane & 15);
    #pragma unroll
    for (int n = 0; n < FN; n++) {
        const int col = c0 + n * 16;
        const float bv = (EPI == 3) ? 0.f : bias[col];
        #pragma unroll
        for (int m = 0; m < FM; m++) {
            const int row = r0 + m * 16;
            const f32x4 a = acc[m][n];
            #pragma unroll
            for (int i = 0; i < 4; i++) {
                const float v = a[i] + bv;
                const size_t off = (size_t)(row + i) * N + col;
                if constexpr (EPI == 0) outb[off] = (bf16)v;
                else if constexpr (EPI == 1) resid[off] += v;
                else if constexpr (EPI == 2) {
                    const float g = 0.5f * v * (1.f + erff(v * 0.70710678118f));
                    outb[off] = (bf16)g;
                } else outf[off] = v;
            }
        }
    }
}

// ---------------- fused non-causal attention (flash-style) ----------------
// grid: (B*NH = 32, S/64 = 16), 256 thr = 4 waves, wave handles 16 q-rows.
__global__ __launch_bounds__(256)
void attn_kernel(const bf16* __restrict__ qkv, bf16* __restrict__ attno)
{
    __shared__ __align__(16) bf16 Vt[64][136];     // V^T chunk: [d][key 0..127], padded
    __shared__ __align__(16) bf16 Plds[4][16][40]; // per-wave P transpose bounce
    const int b = blockIdx.x >> 4, h = blockIdx.x & 15;
    const int qb = blockIdx.y;
    const int tid = threadIdx.x, lane = tid & 63, wave = tid >> 6;
    const bf16* base = qkv + (size_t)b * 1024 * 3072;
    const int qrow0 = qb * 64 + wave * 16;

    bf16x8 aQ[2];
    {
        const int qr = qrow0 + (lane & 15);
        const bf16* qp = base + (size_t)qr * 3072 + h * 64 + ((lane >> 4) << 3);
        aQ[0] = *(const bf16x8*)qp;
        aQ[1] = *(const bf16x8*)(qp + 32);
    }
    float m_i[4] = {-1e30f, -1e30f, -1e30f, -1e30f};
    float l_i[4] = {0.f, 0.f, 0.f, 0.f};
    f32x4 acc[4];
    #pragma unroll
    for (int nb = 0; nb < 4; nb++) acc[nb] = f32x4{0.f, 0.f, 0.f, 0.f};

    for (int ck = 0; ck < 8; ck++) {
        __syncthreads();
        // stage Vt[d][key] for keys ck*128..+128
        #pragma unroll
        for (int p = 0; p < 4; p++) {
            const int idx = p * 256 + tid;
            const int keyl = idx >> 3, dc = idx & 7;
            const bf16x8 v = *(const bf16x8*)&base[(size_t)(ck*128 + keyl) * 3072 + 2048 + h*64 + dc*8];
            #pragma unroll
            for (int e = 0; e < 8; e++) Vt[dc*8 + e][keyl] = v[e];
        }
        __syncthreads();
        for (int kk = 0; kk < 4; kk++) {
            const int key0 = ck * 128 + kk * 32;
            f32x4 s0, s1;
            {
                const int keyA = key0 + (lane & 15);
                const bf16* kp = base + (size_t)keyA * 3072 + 1024 + h * 64 + ((lane >> 4) << 3);
                f32x4 z{0.f, 0.f, 0.f, 0.f};
                z = mfma16(aQ[0], *(const bf16x8*)kp, z);
                z = mfma16(aQ[1], *(const bf16x8*)(kp + 32), z);
                s0 = z;
                const bf16* kp2 = kp + (size_t)16 * 3072;
                f32x4 z2{0.f, 0.f, 0.f, 0.f};
                z2 = mfma16(aQ[0], *(const bf16x8*)kp2, z2);
                z2 = mfma16(aQ[1], *(const bf16x8*)(kp2 + 32), z2);
                s1 = z2;
            }
            float c[4];
            #pragma unroll
            for (int i = 0; i < 4; i++) {
                const float sa = s0[i] * 0.125f, sb = s1[i] * 0.125f;
                float t = fmaxf(sa, sb);
                #pragma unroll
                for (int o = 1; o < 16; o <<= 1) t = fmaxf(t, __shfl_xor(t, o));
                const float mnew = fmaxf(m_i[i], t);
                c[i] = __expf(m_i[i] - mnew);
                const float p0 = __expf(sa - mnew), p1 = __expf(sb - mnew);
                float rs = p0 + p1;
                #pragma unroll
                for (int o = 1; o < 16; o <<= 1) rs += __shfl_xor(rs, o);
                l_i[i] = l_i[i] * c[i] + rs;
                m_i[i] = mnew;
                const int pr = ((lane >> 4) << 2) + i;
                Plds[wave][pr][lane & 15]      = (bf16)p0;
                Plds[wave][pr][16 + (lane & 15)] = (bf16)p1;
            }
            #pragma unroll
            for (int nb = 0; nb < 4; nb++) {
                f32x4 a = acc[nb];
                a[0] *= c[0]; a[1] *= c[1]; a[2] *= c[2]; a[3] *= c[3];
                acc[nb] = a;
            }
            const bf16x8 aP = *(const bf16x8*)&Plds[wave][lane & 15][(lane >> 4) << 3];
            #pragma unroll
            for (int nb = 0; nb < 4; nb++) {
                const bf16x8 bV = *(const bf16x8*)&Vt[nb*16 + (lane & 15)][kk*32 + ((lane >> 4) << 3)];
                acc[nb] = mfma16(aP, bV, acc[nb]);
            }
        }
    }
    #pragma unroll
    for (int nb = 0; nb < 4; nb++) {
        #pragma unroll
        for (int i = 0; i < 4; i++) {
            const int row = qrow0 + ((lane >> 4) << 2) + i;
            const float o = acc[nb][i] / l_i[i];
            attno[(size_t)(b*1024 + row) * 1024 + h*64 + nb*16 + (lane & 15)] = (bf16)o;
        }
    }
}

// ---------------- orchestration ----------------
extern "C" void kernel_launch(void* const* d_in, const int* in_sizes, int n_in,
                              void* d_out, int out_size, void* d_ws, size_t ws_size,
                              hipStream_t stream)
{
    const int*   ids     = (const int*)  d_in[0];
    const float* tok_emb = (const float*)d_in[1];
    const float* pos_emb = (const float*)d_in[2];
    const float* ln1_s   = (const float*)d_in[3];
    const float* ln1_b   = (const float*)d_in[4];
    const float* qkv_w   = (const float*)d_in[5];
    const float* qkv_b   = (const float*)d_in[6];
    const float* out_w   = (const float*)d_in[7];
    const float* out_b   = (const float*)d_in[8];
    const float* ln2_s   = (const float*)d_in[9];
    const float* ln2_b   = (const float*)d_in[10];
    const float* w1      = (const float*)d_in[11];
    const float* b1      = (const float*)d_in[12];
    const float* w2      = (const float*)d_in[13];
    const float* b2      = (const float*)d_in[14];
    const float* lnf_s   = (const float*)d_in[15];
    const float* lnf_b   = (const float*)d_in[16];
    const float* lm_w    = (const float*)d_in[17];

    char* ws = (char*)d_ws;
    float* x    = (float*)ws;  ws += (size_t)2048 * 1024 * 4;
    bf16*  h    = (bf16*)ws;   ws += (size_t)2048 * 1024 * 2;
    bf16*  qkvb = (bf16*)ws;   ws += (size_t)2048 * 3072 * 2;
    bf16*  attno= (bf16*)ws;   ws += (size_t)2048 * 1024 * 2;
    bf16*  ff   = (bf16*)ws;   ws += (size_t)2048 * 4096 * 2;
    bf16*  wT   = (bf16*)ws;   ws += (size_t)32000 * 1024 * 2;

    embed_kernel<<<2048, 256, 0, stream>>>(ids, tok_emb, pos_emb, x);

    for (int l = 0; l < 6; l++) {
        ln_kernel<<<2048, 256, 0, stream>>>(x, ln1_s + l*1024, ln1_b + l*1024, h);
        wcvt_kernel<<<dim3(48, 16), 256, 0, stream>>>(qkv_w + (size_t)l*1024*3072, wT, 1024, 3072);
        gemm_kernel<128,128,0><<<16*24, 256, 0, stream>>>(h, wT, qkv_b + l*3072, nullptr, qkvb, nullptr, 3072, 1024);
        attn_kernel<<<dim3(32, 16), 256, 0, stream>>>(qkvb, attno);
        wcvt_kernel<<<dim3(16, 16), 256, 0, stream>>>(out_w + (size_t)l*1024*1024, wT, 1024, 1024);
        gemm_kernel<128,64,1><<<16*16, 256, 0, stream>>>(attno, wT, out_b + l*1024, x, nullptr, nullptr, 1024, 1024);
        ln_kernel<<<2048, 256, 0, stream>>>(x, ln2_s + l*1024, ln2_b + l*1024, h);
        wcvt_kernel<<<dim3(64, 16), 256, 0, stream>>>(w1 + (size_t)l*1024*4096, wT, 1024, 4096);
        gemm_kernel<128,128,2><<<16*32, 256, 0, stream>>>(h, wT, b1 + l*4096, nullptr, ff, nullptr, 4096, 1024);
        wcvt_kernel<<<dim3(16, 64), 256, 0, stream>>>(w2 + (size_t)l*4096*1024, wT, 4096, 1024);
        gemm_kernel<128,64,1><<<16*16, 256, 0, stream>>>(ff, wT, b2 + l*1024, x, nullptr, nullptr, 1024, 4096);
    }
    ln_kernel<<<2048, 256, 0, stream>>>(x, lnf_s, lnf_b, h);
    wcvt_kernel<<<dim3(500, 16), 256, 0, stream>>>(lm_w, wT, 1024, 32000);
    gemm_kernel<128,128,3><<<16*250, 256, 0, stream>>>(h, wT, nullptr, nullptr, nullptr, (float*)d_out, 32000, 1024);
}